// Round 10
// baseline (94.975 us; speedup 1.0000x reference)
//
#include <hip/hip_runtime.h>
#include <hip/hip_bf16.h>
#include <stdint.h>

#define T_TOK 8192
#define D_IN  512
#define DINT  256
#define NE    8

typedef float f32x4 __attribute__((ext_vector_type(4)));
typedef short bf16x8 __attribute__((ext_vector_type(8)));
typedef unsigned short u16;
typedef unsigned short u16x4 __attribute__((ext_vector_type(4)));

// ws layout (bytes). og overlays xb+f1b (+pad): both dead before fc2 writes og.
#define WS_CNT   0                 // int[8]
#define WS_WP    1024              // f32[16384]         -> 66560
#define WS_BT    66560             // u16[8][8192]       -> 197632
#define WS_F2B   197632            // bf16 fc2 (2MB)     -> 2294784
#define WS_AA    2294784           // bf16 act [16384][256] (8MB) -> 10683392
#define WS_XB    10683392          // bf16 xb [8192][512] (8MB)   -> 19072000
#define WS_F1B   19072000          // bf16 fc1 (4MB)     -> 23266304
#define WS_OG    WS_XB             // bf16 og [16384][512] (16MB) -> 27460608

typedef const __attribute__((address_space(1))) void* gptr_t;
typedef __attribute__((address_space(3))) void* lptr_t;
#define GLL16(g, s) __builtin_amdgcn_global_load_lds((gptr_t)(g), (lptr_t)(s), 16, 0, 0)

static __device__ __forceinline__ u16 f32_bf16(float f) {
    union { float f; uint32_t u; } v; v.f = f;
    uint32_t u = v.u;
    uint32_t r = (u + 0x7FFFu + ((u >> 16) & 1u)) >> 16;   // RTNE
    return (u16)r;
}
static __device__ __forceinline__ float bf16_f32(u16 h) {
    union { uint32_t u; float f; } v; v.u = ((uint32_t)h) << 16; return v.f;
}

// ------- 1. f32 -> bf16 of fc1, fc2; block 0 zeroes cnt (pre-gate) ---------
__global__ __launch_bounds__(256) void cvt_kernel(
    const float* __restrict__ fc1, const float* __restrict__ fc2,
    u16* __restrict__ f1b, u16* __restrict__ f2b, int* __restrict__ cnt)
{
    if (blockIdx.x == 0 && threadIdx.x < NE) cnt[threadIdx.x] = 0;
    const int N1 = NE * 2 * DINT * D_IN / 4;
    const int N2 = NE * D_IN * DINT / 4;
    const int total = N1 + N2;
    for (int i = blockIdx.x * 256 + threadIdx.x; i < total; i += gridDim.x * 256) {
        const float4* s; u16* d; int j;
        if (i < N1) { s = (const float4*)fc1; d = f1b; j = i; }
        else        { s = (const float4*)fc2; d = f2b; j = i - N1; }
        float4 v = s[j];
        u16x4 o;
        o.x = f32_bf16(v.x); o.y = f32_bf16(v.y);
        o.z = f32_bf16(v.z); o.w = f32_bf16(v.w);
        *(u16x4*)&d[(size_t)j * 4] = o;
    }
}

// ------- 2. gate: x -> xb (bf16), logits, softmax, top-2, buckets ----------
__global__ __launch_bounds__(256) void gate_kernel(
    const float* __restrict__ x, const float* __restrict__ wg,
    int* __restrict__ cnt, u16* __restrict__ bt, float* __restrict__ wpair,
    u16* __restrict__ xb)
{
    __shared__ float wgl[NE * D_IN];
    __shared__ float xt[64][67];
    __shared__ float part[256 * 9];
    __shared__ int ecnt[NE];
    __shared__ int gbase[NE];

    const int tid = threadIdx.x;
    const int t0  = blockIdx.x * 64;
    const int tl  = tid & 63;
    const int kq  = tid >> 6;

    for (int i = tid; i < NE * D_IN; i += 256) wgl[i] = wg[i];
    if (tid < NE) ecnt[tid] = 0;

    float acc[NE];
#pragma unroll
    for (int e = 0; e < NE; e++) acc[e] = 0.f;

    for (int c = 0; c < 8; ++c) {
        __syncthreads();
#pragma unroll
        for (int i = 0; i < 4; ++i) {
            int idx = i * 256 + tid;
            int row = idx >> 4, c4 = idx & 15;
            float4 v = *(const float4*)&x[(size_t)(t0 + row) * D_IN + c * 64 + c4 * 4];
            u16x4 o;
            o.x = f32_bf16(v.x); o.y = f32_bf16(v.y);
            o.z = f32_bf16(v.z); o.w = f32_bf16(v.w);
            *(u16x4*)&xb[(size_t)(t0 + row) * D_IN + c * 64 + c4 * 4] = o;
            xt[c4 * 4 + 0][row] = v.x; xt[c4 * 4 + 1][row] = v.y;
            xt[c4 * 4 + 2][row] = v.z; xt[c4 * 4 + 3][row] = v.w;
        }
        __syncthreads();
#pragma unroll
        for (int j = 0; j < 16; ++j) {
            float xv = xt[kq * 16 + j][tl];
#pragma unroll
            for (int e = 0; e < NE; e++)
                acc[e] = fmaf(xv, wgl[e * D_IN + c * 64 + kq * 16 + j], acc[e]);
        }
    }
#pragma unroll
    for (int e = 0; e < NE; e++) part[tid * 9 + e] = acc[e];
    __syncthreads();

    int i1 = 0, i2 = -1, lp1 = 0, lp2 = 0;
    if (tid < 64) {
        float s8[NE];
#pragma unroll
        for (int e = 0; e < NE; e++)
            s8[e] = part[tid * 9 + e] + part[(64 + tid) * 9 + e]
                  + part[(128 + tid) * 9 + e] + part[(192 + tid) * 9 + e];
        float m = s8[0];
#pragma unroll
        for (int e = 1; e < NE; e++) m = fmaxf(m, s8[e]);
        float p[NE], s = 0.f;
#pragma unroll
        for (int e = 0; e < NE; e++) { p[e] = expf(s8[e] - m); s += p[e]; }
        float inv = 1.f / s;
        float v1 = p[0];
#pragma unroll
        for (int e = 1; e < NE; e++) if (p[e] > v1) { v1 = p[e]; i1 = e; }
        float v2 = -1.f;
#pragma unroll
        for (int e = 0; e < NE; e++) if (e != i1 && p[e] > v2) { v2 = p[e]; i2 = e; }
        int t = t0 + tid;
        wpair[2 * t]     = v1 * inv;
        wpair[2 * t + 1] = v2 * inv;
        lp1 = atomicAdd(&ecnt[i1], 1);
        lp2 = atomicAdd(&ecnt[i2], 1);
    }
    __syncthreads();
    if (tid < NE) gbase[tid] = atomicAdd(&cnt[tid], ecnt[tid]);
    __syncthreads();
    if (tid < 64) {
        int t = t0 + tid;
        bt[i1 * T_TOK + gbase[i1] + lp1] = (u16)(2 * t);
        bt[i2 * T_TOK + gbase[i2] + lp2] = (u16)(2 * t + 1);
    }
}

// ---------------- 3. fc1 + GLU -> act (slot-indexed) ----------------
// 128x128 tile, 4 waves (2x2), BK=64 (halves barrier-drain count vs BK=32),
// A+B GLL16-staged into 32.5KB single-buffered LDS, 2 barriers/step.
// N-panel = 64 y-cols [nt*64,+64) + matching gate-cols [256+nt*64,+64).
__global__ __launch_bounds__(256) void fc1_kernel(
    const u16* __restrict__ xb, const u16* __restrict__ f1b,
    const int* __restrict__ cnt, const u16* __restrict__ bt,
    u16* __restrict__ act)
{
    __shared__ __align__(16) u16 asl[2][8 * 512];   // 16KB: [khalf][frag]
    __shared__ __align__(16) u16 bsl[2][8 * 512];   // 16KB
    __shared__ u16 slot_l[128];

    const int bid = blockIdx.x;
    const int e   = bid & 7;                     // XCD pinning
    const int nt  = (bid >> 3) & 3;
    const int mt  = bid >> 5;                    // 0..63
    const int n   = cnt[e];
    const int row0 = mt * 128;
    if (row0 >= n) return;

    const int tid = threadIdx.x;
    const int wv  = tid >> 6, lane = tid & 63;
    const int l15 = lane & 15, lhi = lane >> 4;
    const int wr  = wv >> 1, wc = wv & 1;

    if (tid < 128) {
        int r = row0 + tid;
        slot_l[tid] = bt[e * T_TOK + ((r < n) ? r : (n - 1))];
    }
    __syncthreads();

    // staging sources: wave wv owns A frags {2wv,2wv+1}, B frags {2wv,2wv+1}
    const u16* srcA0 = xb + (size_t)(slot_l[(wv * 2 + 0) * 16 + l15] >> 1) * D_IN + lhi * 8;
    const u16* srcA1 = xb + (size_t)(slot_l[(wv * 2 + 1) * 16 + l15] >> 1) * D_IN + lhi * 8;
    const u16* w1 = f1b + (size_t)e * 512 * 512;
    const int fb0 = wv * 2, fb1 = wv * 2 + 1;
    const int rB0 = ((fb0 < 4) ? (nt * 64 + fb0 * 16) : (256 + nt * 64 + (fb0 - 4) * 16)) + l15;
    const int rB1 = ((fb1 < 4) ? (nt * 64 + fb1 * 16) : (256 + nt * 64 + (fb1 - 4) * 16)) + l15;
    const u16* srcB0 = w1 + (size_t)rB0 * 512 + lhi * 8;
    const u16* srcB1 = w1 + (size_t)rB1 * 512 + lhi * 8;

    f32x4 acc[4][4];
#pragma unroll
    for (int m = 0; m < 4; m++)
#pragma unroll
        for (int nb = 0; nb < 4; nb++) acc[m][nb] = (f32x4)0.f;

    for (int k0 = 0; k0 < 512; k0 += 64) {
        GLL16(srcA0 + k0,      &asl[0][fb0 * 512]);
        GLL16(srcA0 + k0 + 32, &asl[1][fb0 * 512]);
        GLL16(srcA1 + k0,      &asl[0][fb1 * 512]);
        GLL16(srcA1 + k0 + 32, &asl[1][fb1 * 512]);
        GLL16(srcB0 + k0,      &bsl[0][fb0 * 512]);
        GLL16(srcB0 + k0 + 32, &bsl[1][fb0 * 512]);
        GLL16(srcB1 + k0,      &bsl[0][fb1 * 512]);
        GLL16(srcB1 + k0 + 32, &bsl[1][fb1 * 512]);
        __syncthreads();                         // staging complete
#pragma unroll
        for (int h = 0; h < 2; ++h) {
            bf16x8 a[4], b[4];
#pragma unroll
            for (int m = 0; m < 4; m++)
                a[m] = *(const bf16x8*)&asl[h][(wr * 4 + m) * 512 + lane * 8];
            b[0] = *(const bf16x8*)&bsl[h][(wc * 2 + 0) * 512 + lane * 8];
            b[1] = *(const bf16x8*)&bsl[h][(wc * 2 + 1) * 512 + lane * 8];
            b[2] = *(const bf16x8*)&bsl[h][(4 + wc * 2 + 0) * 512 + lane * 8];
            b[3] = *(const bf16x8*)&bsl[h][(4 + wc * 2 + 1) * 512 + lane * 8];
#pragma unroll
            for (int m = 0; m < 4; m++)
#pragma unroll
                for (int nb = 0; nb < 4; nb++)
                    acc[m][nb] = __builtin_amdgcn_mfma_f32_16x16x32_bf16(
                        a[m], b[nb], acc[m][nb], 0, 0, 0);
        }
        __syncthreads();                         // reads done before next stage
    }

    // GLU + store: acc[m][q]=y, acc[m][q+2]=gate, same output col
#pragma unroll
    for (int m = 0; m < 4; m++) {
#pragma unroll
        for (int j = 0; j < 4; j++) {
            int lrow = wr * 64 + m * 16 + lhi * 4 + j;
            if (row0 + lrow < n) {
                int slot = slot_l[lrow];
#pragma unroll
                for (int q = 0; q < 2; q++) {
                    float y = acc[m][q][j], g = acc[m][q + 2][j];
                    float v = y * g / (1.f + __expf(-g));
                    act[(size_t)slot * DINT + nt * 64 + wc * 32 + q * 16 + l15] = f32_bf16(v);
                }
            }
        }
    }
}

// ---------------- 4. fc2 -> og (slot-indexed), BK=64 ----------------
__global__ __launch_bounds__(256) void fc2_kernel(
    const u16* __restrict__ act, const u16* __restrict__ f2b,
    const int* __restrict__ cnt, const u16* __restrict__ bt,
    u16* __restrict__ og)
{
    __shared__ __align__(16) u16 asl[2][8 * 512];
    __shared__ __align__(16) u16 bsl[2][8 * 512];
    __shared__ u16 slot_l[128];

    const int bid = blockIdx.x;
    const int e   = bid & 7;
    const int nt  = (bid >> 3) & 3;
    const int mt  = bid >> 5;
    const int n   = cnt[e];
    const int row0 = mt * 128;
    if (row0 >= n) return;

    const int tid = threadIdx.x;
    const int wv  = tid >> 6, lane = tid & 63;
    const int l15 = lane & 15, lhi = lane >> 4;
    const int wr  = wv >> 1, wc = wv & 1;

    if (tid < 128) {
        int r = row0 + tid;
        slot_l[tid] = bt[e * T_TOK + ((r < n) ? r : (n - 1))];
    }
    __syncthreads();

    const u16* srcA0 = act + (size_t)slot_l[(wv * 2 + 0) * 16 + l15] * DINT + lhi * 8;
    const u16* srcA1 = act + (size_t)slot_l[(wv * 2 + 1) * 16 + l15] * DINT + lhi * 8;
    const u16* w2 = f2b + (size_t)e * D_IN * DINT;
    const int fb0 = wv * 2, fb1 = wv * 2 + 1;
    const u16* srcB0 = w2 + (size_t)(nt * 128 + fb0 * 16 + l15) * DINT + lhi * 8;
    const u16* srcB1 = w2 + (size_t)(nt * 128 + fb1 * 16 + l15) * DINT + lhi * 8;

    f32x4 acc[4][4];
#pragma unroll
    for (int m = 0; m < 4; m++)
#pragma unroll
        for (int nb = 0; nb < 4; nb++) acc[m][nb] = (f32x4)0.f;

    for (int k0 = 0; k0 < 256; k0 += 64) {
        GLL16(srcA0 + k0,      &asl[0][fb0 * 512]);
        GLL16(srcA0 + k0 + 32, &asl[1][fb0 * 512]);
        GLL16(srcA1 + k0,      &asl[0][fb1 * 512]);
        GLL16(srcA1 + k0 + 32, &asl[1][fb1 * 512]);
        GLL16(srcB0 + k0,      &bsl[0][fb0 * 512]);
        GLL16(srcB0 + k0 + 32, &bsl[1][fb0 * 512]);
        GLL16(srcB1 + k0,      &bsl[0][fb1 * 512]);
        GLL16(srcB1 + k0 + 32, &bsl[1][fb1 * 512]);
        __syncthreads();
#pragma unroll
        for (int h = 0; h < 2; ++h) {
            bf16x8 a[4], b[4];
#pragma unroll
            for (int m = 0; m < 4; m++)
                a[m] = *(const bf16x8*)&asl[h][(wr * 4 + m) * 512 + lane * 8];
#pragma unroll
            for (int nb = 0; nb < 4; nb++)
                b[nb] = *(const bf16x8*)&bsl[h][(wc * 4 + nb) * 512 + lane * 8];
#pragma unroll
            for (int m = 0; m < 4; m++)
#pragma unroll
                for (int nb = 0; nb < 4; nb++)
                    acc[m][nb] = __builtin_amdgcn_mfma_f32_16x16x32_bf16(
                        a[m], b[nb], acc[m][nb], 0, 0, 0);
        }
        __syncthreads();
    }

#pragma unroll
    for (int m = 0; m < 4; m++) {
#pragma unroll
        for (int j = 0; j < 4; j++) {
            int lrow = wr * 64 + m * 16 + lhi * 4 + j;
            if (row0 + lrow < n) {
                int slot = slot_l[lrow];
                u16* dst = og + (size_t)slot * D_IN + nt * 128 + wc * 64 + l15;
#pragma unroll
                for (int nb = 0; nb < 4; nb++)
                    dst[nb * 16] = f32_bf16(acc[m][nb][j]);
            }
        }
    }
}

// ---------------- 5. combine: z[t] = w0*og[2t] + w1*og[2t+1] ----------------
__global__ __launch_bounds__(256) void combine_kernel(
    const u16* __restrict__ og, const float* __restrict__ wpair,
    float* __restrict__ out)
{
    int idx = blockIdx.x * 256 + threadIdx.x;
    int t  = idx >> 6;
    int c8 = (idx & 63) * 8;
    float w0 = wpair[2 * t], w1 = wpair[2 * t + 1];
    bf16x8 a = *(const bf16x8*)&og[(size_t)(2 * t) * D_IN + c8];
    bf16x8 b = *(const bf16x8*)&og[(size_t)(2 * t + 1) * D_IN + c8];
    float4 o0, o1;
#pragma unroll
    for (int j = 0; j < 4; j++) {
        o0[j] = w0 * bf16_f32((u16)a[j])     + w1 * bf16_f32((u16)b[j]);
        o1[j] = w0 * bf16_f32((u16)a[j + 4]) + w1 * bf16_f32((u16)b[j + 4]);
    }
    float* orow = out + (size_t)t * D_IN + c8;
    *(float4*)orow = o0;
    *(float4*)(orow + 4) = o1;
}

// ---------------- launch ----------------
extern "C" void kernel_launch(void* const* d_in, const int* in_sizes, int n_in,
                              void* d_out, int out_size, void* d_ws, size_t ws_size,
                              hipStream_t stream) {
    const float* x   = (const float*)d_in[0];
    const float* wg  = (const float*)d_in[1];
    const float* fc1 = (const float*)d_in[2];
    const float* fc2 = (const float*)d_in[3];
    float* out = (float*)d_out;
    char* ws = (char*)d_ws;

    int*   cnt   = (int*)(ws + WS_CNT);
    float* wpair = (float*)(ws + WS_WP);
    u16*   bt    = (u16*)(ws + WS_BT);
    u16*   f2b   = (u16*)(ws + WS_F2B);
    u16*   aact  = (u16*)(ws + WS_AA);
    u16*   xb    = (u16*)(ws + WS_XB);
    u16*   f1b   = (u16*)(ws + WS_F1B);
    u16*   og    = (u16*)(ws + WS_OG);

    cvt_kernel<<<1024, 256, 0, stream>>>(fc1, fc2, f1b, f2b, cnt);
    gate_kernel<<<T_TOK / 64, 256, 0, stream>>>(x, wg, cnt, bt, wpair, xb);
    fc1_kernel<<<2048, 256, 0, stream>>>(xb, f1b, cnt, bt, aact);
    fc2_kernel<<<2048, 256, 0, stream>>>(aact, f2b, cnt, bt, og);
    combine_kernel<<<T_TOK * (D_IN / 8) / 256, 256, 0, stream>>>(og, wpair, out);
}

// Round 11
// 92.234 us; speedup vs baseline: 1.0297x; 1.0297x over previous
//
#include <hip/hip_runtime.h>
#include <hip/hip_bf16.h>
#include <stdint.h>

#define T_TOK 8192
#define D_IN  512
#define DINT  256
#define NE    8

typedef float f32x4 __attribute__((ext_vector_type(4)));
typedef short bf16x8 __attribute__((ext_vector_type(8)));
typedef unsigned short u16;
typedef unsigned short u16x4 __attribute__((ext_vector_type(4)));

// ws layout (bytes)
#define WS_CNT   0                 // int[8]
#define WS_WP    1024              // f32[16384]         -> 66560
#define WS_BT    66560             // u16[8][8192]       -> 197632
#define WS_F2B   197632            // bf16 fc2 (2MB)     -> 2294784
#define WS_AA    2294784           // bf16 act [16384][256] (8MB) -> 10683392
#define WS_XB    10683392          // bf16 xb [8192][512] (8MB)   -> 19072000
#define WS_F1B   19072000          // bf16 fc1 (4MB)     -> 23266304

typedef const __attribute__((address_space(1))) void* gptr_t;
typedef __attribute__((address_space(3))) void* lptr_t;
#define GLL16(g, s) __builtin_amdgcn_global_load_lds((gptr_t)(g), (lptr_t)(s), 16, 0, 0)

static __device__ __forceinline__ u16 f32_bf16(float f) {
    union { float f; uint32_t u; } v; v.f = f;
    uint32_t u = v.u;
    uint32_t r = (u + 0x7FFFu + ((u >> 16) & 1u)) >> 16;   // RTNE
    return (u16)r;
}

// -- 1. f32->bf16 of fc1/fc2; zero cnt + d_out (both pre-consumers) ---------
__global__ __launch_bounds__(256) void cvt_kernel(
    const float* __restrict__ fc1, const float* __restrict__ fc2,
    u16* __restrict__ f1b, u16* __restrict__ f2b, int* __restrict__ cnt,
    float* __restrict__ out)
{
    if (blockIdx.x == 0 && threadIdx.x < NE) cnt[threadIdx.x] = 0;
    const int N1 = NE * 2 * DINT * D_IN / 4;
    const int N2 = NE * D_IN * DINT / 4;
    const int total = N1 + N2;
    for (int i = blockIdx.x * 256 + threadIdx.x; i < total; i += gridDim.x * 256) {
        const float4* s; u16* d; int j;
        if (i < N1) { s = (const float4*)fc1; d = f1b; j = i; }
        else        { s = (const float4*)fc2; d = f2b; j = i - N1; }
        float4 v = s[j];
        u16x4 o;
        o.x = f32_bf16(v.x); o.y = f32_bf16(v.y);
        o.z = f32_bf16(v.z); o.w = f32_bf16(v.w);
        *(u16x4*)&d[(size_t)j * 4] = o;
    }
    // zero d_out (fc2 accumulates into it atomically)
    const float4 z4 = {0.f, 0.f, 0.f, 0.f};
    const int NO = T_TOK * D_IN / 4;
    for (int i = blockIdx.x * 256 + threadIdx.x; i < NO; i += gridDim.x * 256)
        ((float4*)out)[i] = z4;
}

// -- 2. gate: 32 tokens/block (256 blocks), x->xb, logits, top-2, buckets ---
__global__ __launch_bounds__(256) void gate_kernel(
    const float* __restrict__ x, const float* __restrict__ wg,
    int* __restrict__ cnt, u16* __restrict__ bt, float* __restrict__ wpair,
    u16* __restrict__ xb)
{
    __shared__ float wgl[NE * D_IN];     // 16 KB
    __shared__ float xt[256][33];        // 33.8 KB [local k][token]
    __shared__ float part[256 * 9];      // 9.2 KB
    __shared__ int ecnt[NE];
    __shared__ int gbase[NE];

    const int tid = threadIdx.x;
    const int t0  = blockIdx.x * 32;
    const int tl  = tid & 31;
    const int kq  = tid >> 5;            // 0..7

    for (int i = tid; i < NE * D_IN; i += 256) wgl[i] = wg[i];
    if (tid < NE) ecnt[tid] = 0;

    float acc[NE];
#pragma unroll
    for (int e = 0; e < NE; e++) acc[e] = 0.f;

    for (int c = 0; c < 2; ++c) {
        __syncthreads();
        // stage 32 tokens x 256 k (f32) transposed; also write xb (bf16)
#pragma unroll
        for (int i = 0; i < 8; ++i) {
            int idx = i * 256 + tid;          // 2048 float4
            int row = idx >> 6, c4 = idx & 63;
            float4 v = *(const float4*)&x[(size_t)(t0 + row) * D_IN + c * 256 + c4 * 4];
            u16x4 o;
            o.x = f32_bf16(v.x); o.y = f32_bf16(v.y);
            o.z = f32_bf16(v.z); o.w = f32_bf16(v.w);
            *(u16x4*)&xb[(size_t)(t0 + row) * D_IN + c * 256 + c4 * 4] = o;
            xt[c4 * 4 + 0][row] = v.x; xt[c4 * 4 + 1][row] = v.y;
            xt[c4 * 4 + 2][row] = v.z; xt[c4 * 4 + 3][row] = v.w;
        }
        __syncthreads();
#pragma unroll
        for (int j = 0; j < 32; ++j) {
            float xv = xt[kq * 32 + j][tl];
#pragma unroll
            for (int e = 0; e < NE; e++)
                acc[e] = fmaf(xv, wgl[e * D_IN + c * 256 + kq * 32 + j], acc[e]);
        }
    }
#pragma unroll
    for (int e = 0; e < NE; e++) part[tid * 9 + e] = acc[e];
    __syncthreads();

    int i1 = 0, i2 = -1, lp1 = 0, lp2 = 0;
    if (tid < 32) {
        float s8[NE];
#pragma unroll
        for (int e = 0; e < NE; e++) {
            float s = 0.f;
#pragma unroll
            for (int q = 0; q < 8; q++) s += part[(q * 32 + tid) * 9 + e];
            s8[e] = s;
        }
        float m = s8[0];
#pragma unroll
        for (int e = 1; e < NE; e++) m = fmaxf(m, s8[e]);
        float p[NE], s = 0.f;
#pragma unroll
        for (int e = 0; e < NE; e++) { p[e] = expf(s8[e] - m); s += p[e]; }
        float inv = 1.f / s;
        float v1 = p[0];
#pragma unroll
        for (int e = 1; e < NE; e++) if (p[e] > v1) { v1 = p[e]; i1 = e; }
        float v2 = -1.f;
#pragma unroll
        for (int e = 0; e < NE; e++) if (e != i1 && p[e] > v2) { v2 = p[e]; i2 = e; }
        int t = t0 + tid;
        wpair[2 * t]     = v1 * inv;
        wpair[2 * t + 1] = v2 * inv;
        lp1 = atomicAdd(&ecnt[i1], 1);
        lp2 = atomicAdd(&ecnt[i2], 1);
    }
    __syncthreads();
    if (tid < NE) gbase[tid] = atomicAdd(&cnt[tid], ecnt[tid]);
    __syncthreads();
    if (tid < 32) {
        int t = t0 + tid;
        bt[i1 * T_TOK + gbase[i1] + lp1] = (u16)(2 * t);
        bt[i2 * T_TOK + gbase[i2] + lp2] = (u16)(2 * t + 1);
    }
}

// ---------------- 3. fc1 + GLU -> act (slot-indexed) ----------------
// round-9 proven structure: 128x128 tile, 4 waves (2x2), BK=32, A+B GLL16
// into 16.25KB single-buffered LDS, 2 barriers/step.
__global__ __launch_bounds__(256) void fc1_kernel(
    const u16* __restrict__ xb, const u16* __restrict__ f1b,
    const int* __restrict__ cnt, const u16* __restrict__ bt,
    u16* __restrict__ act)
{
    __shared__ __align__(16) u16 asl[8 * 512];
    __shared__ __align__(16) u16 bsl[8 * 512];
    __shared__ u16 slot_l[128];

    const int bid = blockIdx.x;
    const int e   = bid & 7;                     // XCD pinning
    const int nt  = (bid >> 3) & 3;
    const int mt  = bid >> 5;                    // 0..63
    const int n   = cnt[e];
    const int row0 = mt * 128;
    if (row0 >= n) return;

    const int tid = threadIdx.x;
    const int wv  = tid >> 6, lane = tid & 63;
    const int l15 = lane & 15, lhi = lane >> 4;
    const int wr  = wv >> 1, wc = wv & 1;

    if (tid < 128) {
        int r = row0 + tid;
        slot_l[tid] = bt[e * T_TOK + ((r < n) ? r : (n - 1))];
    }
    __syncthreads();

    const u16* srcA0 = xb + (size_t)(slot_l[(wv * 2 + 0) * 16 + l15] >> 1) * D_IN + lhi * 8;
    const u16* srcA1 = xb + (size_t)(slot_l[(wv * 2 + 1) * 16 + l15] >> 1) * D_IN + lhi * 8;
    const u16* w1 = f1b + (size_t)e * 512 * 512;
    const int fb0 = wv * 2, fb1 = wv * 2 + 1;
    const int rB0 = ((fb0 < 4) ? (nt * 64 + fb0 * 16) : (256 + nt * 64 + (fb0 - 4) * 16)) + l15;
    const int rB1 = ((fb1 < 4) ? (nt * 64 + fb1 * 16) : (256 + nt * 64 + (fb1 - 4) * 16)) + l15;
    const u16* srcB0 = w1 + (size_t)rB0 * 512 + lhi * 8;
    const u16* srcB1 = w1 + (size_t)rB1 * 512 + lhi * 8;

    f32x4 acc[4][4];
#pragma unroll
    for (int m = 0; m < 4; m++)
#pragma unroll
        for (int nb = 0; nb < 4; nb++) acc[m][nb] = (f32x4)0.f;

    for (int k0 = 0; k0 < 512; k0 += 32) {
        GLL16(srcA0 + k0, &asl[fb0 * 512]);
        GLL16(srcA1 + k0, &asl[fb1 * 512]);
        GLL16(srcB0 + k0, &bsl[fb0 * 512]);
        GLL16(srcB1 + k0, &bsl[fb1 * 512]);
        __syncthreads();
        bf16x8 a[4], b[4];
#pragma unroll
        for (int m = 0; m < 4; m++)
            a[m] = *(const bf16x8*)&asl[(wr * 4 + m) * 512 + lane * 8];
        b[0] = *(const bf16x8*)&bsl[(wc * 2 + 0) * 512 + lane * 8];
        b[1] = *(const bf16x8*)&bsl[(wc * 2 + 1) * 512 + lane * 8];
        b[2] = *(const bf16x8*)&bsl[(4 + wc * 2 + 0) * 512 + lane * 8];
        b[3] = *(const bf16x8*)&bsl[(4 + wc * 2 + 1) * 512 + lane * 8];
#pragma unroll
        for (int m = 0; m < 4; m++)
#pragma unroll
            for (int nb = 0; nb < 4; nb++)
                acc[m][nb] = __builtin_amdgcn_mfma_f32_16x16x32_bf16(
                    a[m], b[nb], acc[m][nb], 0, 0, 0);
        __syncthreads();
    }

#pragma unroll
    for (int m = 0; m < 4; m++) {
#pragma unroll
        for (int j = 0; j < 4; j++) {
            int lrow = wr * 64 + m * 16 + lhi * 4 + j;
            if (row0 + lrow < n) {
                int slot = slot_l[lrow];
#pragma unroll
                for (int q = 0; q < 2; q++) {
                    float y = acc[m][q][j], g = acc[m][q + 2][j];
                    float v = y * g / (1.f + __expf(-g));
                    act[(size_t)slot * DINT + nt * 64 + wc * 32 + q * 16 + l15] = f32_bf16(v);
                }
            }
        }
    }
}

// ------ 4. fc2 + weighted combine -> out (f32 atomics, 2 adds/elem) --------
__global__ __launch_bounds__(256) void fc2_kernel(
    const u16* __restrict__ act, const u16* __restrict__ f2b,
    const int* __restrict__ cnt, const u16* __restrict__ bt,
    const float* __restrict__ wpair, float* __restrict__ out)
{
    __shared__ __align__(16) u16 asl[8 * 512];
    __shared__ __align__(16) u16 bsl[8 * 512];
    __shared__ u16 slot_l[128];
    __shared__ float w_l[128];

    const int bid = blockIdx.x;
    const int e   = bid & 7;
    const int nt  = (bid >> 3) & 3;
    const int mt  = bid >> 5;
    const int n   = cnt[e];
    const int row0 = mt * 128;
    if (row0 >= n) return;

    const int tid = threadIdx.x;
    const int wv  = tid >> 6, lane = tid & 63;
    const int l15 = lane & 15, lhi = lane >> 4;
    const int wr  = wv >> 1, wc = wv & 1;

    if (tid < 128) {
        int r = row0 + tid;
        int slot = bt[e * T_TOK + ((r < n) ? r : (n - 1))];
        slot_l[tid] = (u16)slot;
        w_l[tid] = wpair[slot];
    }
    __syncthreads();

    const u16* srcA0 = act + (size_t)slot_l[(wv * 2 + 0) * 16 + l15] * DINT + lhi * 8;
    const u16* srcA1 = act + (size_t)slot_l[(wv * 2 + 1) * 16 + l15] * DINT + lhi * 8;
    const u16* w2 = f2b + (size_t)e * D_IN * DINT;
    const int fb0 = wv * 2, fb1 = wv * 2 + 1;
    const u16* srcB0 = w2 + (size_t)(nt * 128 + fb0 * 16 + l15) * DINT + lhi * 8;
    const u16* srcB1 = w2 + (size_t)(nt * 128 + fb1 * 16 + l15) * DINT + lhi * 8;

    f32x4 acc[4][4];
#pragma unroll
    for (int m = 0; m < 4; m++)
#pragma unroll
        for (int nb = 0; nb < 4; nb++) acc[m][nb] = (f32x4)0.f;

    for (int k0 = 0; k0 < 256; k0 += 32) {
        GLL16(srcA0 + k0, &asl[fb0 * 512]);
        GLL16(srcA1 + k0, &asl[fb1 * 512]);
        GLL16(srcB0 + k0, &bsl[fb0 * 512]);
        GLL16(srcB1 + k0, &bsl[fb1 * 512]);
        __syncthreads();
        bf16x8 a[4], b[4];
#pragma unroll
        for (int m = 0; m < 4; m++)
            a[m] = *(const bf16x8*)&asl[(wr * 4 + m) * 512 + lane * 8];
#pragma unroll
        for (int nb = 0; nb < 4; nb++)
            b[nb] = *(const bf16x8*)&bsl[(wc * 4 + nb) * 512 + lane * 8];
#pragma unroll
        for (int m = 0; m < 4; m++)
#pragma unroll
            for (int nb = 0; nb < 4; nb++)
                acc[m][nb] = __builtin_amdgcn_mfma_f32_16x16x32_bf16(
                    a[m], b[nb], acc[m][nb], 0, 0, 0);
        __syncthreads();
    }

    // epilogue: out[t] += w * O  (each element gets exactly 2 adds globally;
    // IEEE a+b == b+a -> replay-deterministic)
#pragma unroll
    for (int m = 0; m < 4; m++) {
#pragma unroll
        for (int j = 0; j < 4; j++) {
            int lrow = wr * 64 + m * 16 + lhi * 4 + j;
            if (row0 + lrow < n) {
                int slot = slot_l[lrow];
                float wt = w_l[lrow];
                float* dst = out + (size_t)(slot >> 1) * D_IN + nt * 128 + wc * 64 + l15;
#pragma unroll
                for (int nb = 0; nb < 4; nb++)
                    unsafeAtomicAdd(&dst[nb * 16], wt * acc[m][nb][j]);
            }
        }
    }
}

// ---------------- launch ----------------
extern "C" void kernel_launch(void* const* d_in, const int* in_sizes, int n_in,
                              void* d_out, int out_size, void* d_ws, size_t ws_size,
                              hipStream_t stream) {
    const float* x   = (const float*)d_in[0];
    const float* wg  = (const float*)d_in[1];
    const float* fc1 = (const float*)d_in[2];
    const float* fc2 = (const float*)d_in[3];
    float* out = (float*)d_out;
    char* ws = (char*)d_ws;

    int*   cnt   = (int*)(ws + WS_CNT);
    float* wpair = (float*)(ws + WS_WP);
    u16*   bt    = (u16*)(ws + WS_BT);
    u16*   f2b   = (u16*)(ws + WS_F2B);
    u16*   aact  = (u16*)(ws + WS_AA);
    u16*   xb    = (u16*)(ws + WS_XB);
    u16*   f1b   = (u16*)(ws + WS_F1B);

    cvt_kernel<<<1024, 256, 0, stream>>>(fc1, fc2, f1b, f2b, cnt, out);
    gate_kernel<<<T_TOK / 32, 256, 0, stream>>>(x, wg, cnt, bt, wpair, xb);
    fc1_kernel<<<2048, 256, 0, stream>>>(xb, f1b, cnt, bt, aact);
    fc2_kernel<<<2048, 256, 0, stream>>>(aact, f2b, cnt, bt, wpair, out);
}

// Round 12
// 89.432 us; speedup vs baseline: 1.0620x; 1.0313x over previous
//
#include <hip/hip_runtime.h>
#include <hip/hip_bf16.h>
#include <stdint.h>

#define T_TOK 8192
#define D_IN  512
#define DINT  256
#define NE    8

typedef float f32x4 __attribute__((ext_vector_type(4)));
typedef short bf16x8 __attribute__((ext_vector_type(8)));
typedef unsigned short u16;
typedef unsigned short u16x4 __attribute__((ext_vector_type(4)));

// ws layout (bytes). og overlays xb+f1b (+pad): both dead before fc2 writes og.
#define WS_CNT   0                 // int[8]
#define WS_WP    1024              // f32[16384]         -> 66560
#define WS_BT    66560             // u16[8][8192]       -> 197632
#define WS_F2B   197632            // bf16 fc2 (2MB)     -> 2294784
#define WS_AA    2294784           // bf16 act [16384][256] (8MB) -> 10683392
#define WS_XB    10683392          // bf16 xb [8192][512] (8MB)   -> 19072000
#define WS_F1B   19072000          // bf16 fc1 (4MB)     -> 23266304
#define WS_OG    WS_XB             // bf16 og [16384][512] overlay

typedef const __attribute__((address_space(1))) void* gptr_t;
typedef __attribute__((address_space(3))) void* lptr_t;
#define GLL16(g, s) __builtin_amdgcn_global_load_lds((gptr_t)(g), (lptr_t)(s), 16, 0, 0)

static __device__ __forceinline__ u16 f32_bf16(float f) {
    union { float f; uint32_t u; } v; v.f = f;
    uint32_t u = v.u;
    uint32_t r = (u + 0x7FFFu + ((u >> 16) & 1u)) >> 16;   // RTNE
    return (u16)r;
}
static __device__ __forceinline__ float bf16_f32(u16 h) {
    union { uint32_t u; float f; } v; v.u = ((uint32_t)h) << 16; return v.f;
}

// ------- 1. f32 -> bf16 of fc1, fc2; block 0 zeroes cnt (pre-gate) ---------
__global__ __launch_bounds__(256) void cvt_kernel(
    const float* __restrict__ fc1, const float* __restrict__ fc2,
    u16* __restrict__ f1b, u16* __restrict__ f2b, int* __restrict__ cnt)
{
    if (blockIdx.x == 0 && threadIdx.x < NE) cnt[threadIdx.x] = 0;
    const int N1 = NE * 2 * DINT * D_IN / 4;
    const int N2 = NE * D_IN * DINT / 4;
    const int total = N1 + N2;
    for (int i = blockIdx.x * 256 + threadIdx.x; i < total; i += gridDim.x * 256) {
        const float4* s; u16* d; int j;
        if (i < N1) { s = (const float4*)fc1; d = f1b; j = i; }
        else        { s = (const float4*)fc2; d = f2b; j = i - N1; }
        float4 v = s[j];
        u16x4 o;
        o.x = f32_bf16(v.x); o.y = f32_bf16(v.y);
        o.z = f32_bf16(v.z); o.w = f32_bf16(v.w);
        *(u16x4*)&d[(size_t)j * 4] = o;
    }
}

// ------- 2. gate: x -> xb (bf16), logits, softmax, top-2, buckets ----------
__global__ __launch_bounds__(256) void gate_kernel(
    const float* __restrict__ x, const float* __restrict__ wg,
    int* __restrict__ cnt, u16* __restrict__ bt, float* __restrict__ wpair,
    u16* __restrict__ xb)
{
    __shared__ float wgl[NE * D_IN];
    __shared__ float xt[64][67];
    __shared__ float part[256 * 9];
    __shared__ int ecnt[NE];
    __shared__ int gbase[NE];

    const int tid = threadIdx.x;
    const int t0  = blockIdx.x * 64;
    const int tl  = tid & 63;
    const int kq  = tid >> 6;

    for (int i = tid; i < NE * D_IN; i += 256) wgl[i] = wg[i];
    if (tid < NE) ecnt[tid] = 0;

    float acc[NE];
#pragma unroll
    for (int e = 0; e < NE; e++) acc[e] = 0.f;

    for (int c = 0; c < 8; ++c) {
        __syncthreads();
#pragma unroll
        for (int i = 0; i < 4; ++i) {
            int idx = i * 256 + tid;
            int row = idx >> 4, c4 = idx & 15;
            float4 v = *(const float4*)&x[(size_t)(t0 + row) * D_IN + c * 64 + c4 * 4];
            u16x4 o;
            o.x = f32_bf16(v.x); o.y = f32_bf16(v.y);
            o.z = f32_bf16(v.z); o.w = f32_bf16(v.w);
            *(u16x4*)&xb[(size_t)(t0 + row) * D_IN + c * 64 + c4 * 4] = o;
            xt[c4 * 4 + 0][row] = v.x; xt[c4 * 4 + 1][row] = v.y;
            xt[c4 * 4 + 2][row] = v.z; xt[c4 * 4 + 3][row] = v.w;
        }
        __syncthreads();
#pragma unroll
        for (int j = 0; j < 16; ++j) {
            float xv = xt[kq * 16 + j][tl];
#pragma unroll
            for (int e = 0; e < NE; e++)
                acc[e] = fmaf(xv, wgl[e * D_IN + c * 64 + kq * 16 + j], acc[e]);
        }
    }
#pragma unroll
    for (int e = 0; e < NE; e++) part[tid * 9 + e] = acc[e];
    __syncthreads();

    int i1 = 0, i2 = -1, lp1 = 0, lp2 = 0;
    if (tid < 64) {
        float s8[NE];
#pragma unroll
        for (int e = 0; e < NE; e++)
            s8[e] = part[tid * 9 + e] + part[(64 + tid) * 9 + e]
                  + part[(128 + tid) * 9 + e] + part[(192 + tid) * 9 + e];
        float m = s8[0];
#pragma unroll
        for (int e = 1; e < NE; e++) m = fmaxf(m, s8[e]);
        float p[NE], s = 0.f;
#pragma unroll
        for (int e = 0; e < NE; e++) { p[e] = expf(s8[e] - m); s += p[e]; }
        float inv = 1.f / s;
        float v1 = p[0];
#pragma unroll
        for (int e = 1; e < NE; e++) if (p[e] > v1) { v1 = p[e]; i1 = e; }
        float v2 = -1.f;
#pragma unroll
        for (int e = 0; e < NE; e++) if (e != i1 && p[e] > v2) { v2 = p[e]; i2 = e; }
        int t = t0 + tid;
        wpair[2 * t]     = v1 * inv;
        wpair[2 * t + 1] = v2 * inv;
        lp1 = atomicAdd(&ecnt[i1], 1);
        lp2 = atomicAdd(&ecnt[i2], 1);
    }
    __syncthreads();
    if (tid < NE) gbase[tid] = atomicAdd(&cnt[tid], ecnt[tid]);
    __syncthreads();
    if (tid < 64) {
        int t = t0 + tid;
        bt[i1 * T_TOK + gbase[i1] + lp1] = (u16)(2 * t);
        bt[i2 * T_TOK + gbase[i2] + lp2] = (u16)(2 * t + 1);
    }
}

// ---------------- 3. fc1 + GLU -> act (slot-indexed) ----------------
// round-9 structure + 2-phase pipeline: issue next-tile GLL16 BEFORE the
// current tile's ds_read+MFMA, ONE barrier per K-step (drain covered by MFMA).
__global__ __launch_bounds__(256) void fc1_kernel(
    const u16* __restrict__ xb, const u16* __restrict__ f1b,
    const int* __restrict__ cnt, const u16* __restrict__ bt,
    u16* __restrict__ act)
{
    __shared__ __align__(16) u16 asl[2][8 * 512];   // 2 x 8KB
    __shared__ __align__(16) u16 bsl[2][8 * 512];   // 2 x 8KB
    __shared__ u16 slot_l[128];

    const int bid = blockIdx.x;
    const int e   = bid & 7;                     // XCD pinning
    const int nt  = (bid >> 3) & 3;
    const int mt  = bid >> 5;                    // 0..63
    const int n   = cnt[e];
    const int row0 = mt * 128;
    if (row0 >= n) return;

    const int tid = threadIdx.x;
    const int wv  = tid >> 6, lane = tid & 63;
    const int l15 = lane & 15, lhi = lane >> 4;
    const int wr  = wv >> 1, wc = wv & 1;

    if (tid < 128) {
        int r = row0 + tid;
        slot_l[tid] = bt[e * T_TOK + ((r < n) ? r : (n - 1))];
    }
    __syncthreads();

    const u16* srcA0 = xb + (size_t)(slot_l[(wv * 2 + 0) * 16 + l15] >> 1) * D_IN + lhi * 8;
    const u16* srcA1 = xb + (size_t)(slot_l[(wv * 2 + 1) * 16 + l15] >> 1) * D_IN + lhi * 8;
    const u16* w1 = f1b + (size_t)e * 512 * 512;
    const int fb0 = wv * 2, fb1 = wv * 2 + 1;
    const int rB0 = ((fb0 < 4) ? (nt * 64 + fb0 * 16) : (256 + nt * 64 + (fb0 - 4) * 16)) + l15;
    const int rB1 = ((fb1 < 4) ? (nt * 64 + fb1 * 16) : (256 + nt * 64 + (fb1 - 4) * 16)) + l15;
    const u16* srcB0 = w1 + (size_t)rB0 * 512 + lhi * 8;
    const u16* srcB1 = w1 + (size_t)rB1 * 512 + lhi * 8;

    f32x4 acc[4][4];
#pragma unroll
    for (int m = 0; m < 4; m++)
#pragma unroll
        for (int nb = 0; nb < 4; nb++) acc[m][nb] = (f32x4)0.f;

    // prologue: stage K-step 0 into buffer 0
    GLL16(srcA0, &asl[0][fb0 * 512]);
    GLL16(srcA1, &asl[0][fb1 * 512]);
    GLL16(srcB0, &bsl[0][fb0 * 512]);
    GLL16(srcB1, &bsl[0][fb1 * 512]);
    __syncthreads();

#pragma unroll
    for (int ks = 0; ks < 16; ++ks) {
        const int cur = ks & 1;
        if (ks < 15) {                           // issue next-tile loads first
            const int kn = (ks + 1) * 32;
            GLL16(srcA0 + kn, &asl[cur ^ 1][fb0 * 512]);
            GLL16(srcA1 + kn, &asl[cur ^ 1][fb1 * 512]);
            GLL16(srcB0 + kn, &bsl[cur ^ 1][fb0 * 512]);
            GLL16(srcB1 + kn, &bsl[cur ^ 1][fb1 * 512]);
        }
        bf16x8 a[4], b[4];
#pragma unroll
        for (int m = 0; m < 4; m++)
            a[m] = *(const bf16x8*)&asl[cur][(wr * 4 + m) * 512 + lane * 8];
        b[0] = *(const bf16x8*)&bsl[cur][(wc * 2 + 0) * 512 + lane * 8];
        b[1] = *(const bf16x8*)&bsl[cur][(wc * 2 + 1) * 512 + lane * 8];
        b[2] = *(const bf16x8*)&bsl[cur][(4 + wc * 2 + 0) * 512 + lane * 8];
        b[3] = *(const bf16x8*)&bsl[cur][(4 + wc * 2 + 1) * 512 + lane * 8];
#pragma unroll
        for (int m = 0; m < 4; m++)
#pragma unroll
            for (int nb = 0; nb < 4; nb++)
                acc[m][nb] = __builtin_amdgcn_mfma_f32_16x16x32_bf16(
                    a[m], b[nb], acc[m][nb], 0, 0, 0);
        __syncthreads();   // drains next-tile loads (covered by MFMA) + read fence
    }

    // GLU + store
#pragma unroll
    for (int m = 0; m < 4; m++) {
#pragma unroll
        for (int j = 0; j < 4; j++) {
            int lrow = wr * 64 + m * 16 + lhi * 4 + j;
            if (row0 + lrow < n) {
                int slot = slot_l[lrow];
#pragma unroll
                for (int q = 0; q < 2; q++) {
                    float y = acc[m][q][j], g = acc[m][q + 2][j];
                    float v = y * g / (1.f + __expf(-g));
                    act[(size_t)slot * DINT + nt * 64 + wc * 32 + q * 16 + l15] = f32_bf16(v);
                }
            }
        }
    }
}

// ---------------- 4. fc2 -> og (slot-indexed), 2-phase ----------------
__global__ __launch_bounds__(256) void fc2_kernel(
    const u16* __restrict__ act, const u16* __restrict__ f2b,
    const int* __restrict__ cnt, const u16* __restrict__ bt,
    u16* __restrict__ og)
{
    __shared__ __align__(16) u16 asl[2][8 * 512];
    __shared__ __align__(16) u16 bsl[2][8 * 512];
    __shared__ u16 slot_l[128];

    const int bid = blockIdx.x;
    const int e   = bid & 7;
    const int nt  = (bid >> 3) & 3;
    const int mt  = bid >> 5;
    const int n   = cnt[e];
    const int row0 = mt * 128;
    if (row0 >= n) return;

    const int tid = threadIdx.x;
    const int wv  = tid >> 6, lane = tid & 63;
    const int l15 = lane & 15, lhi = lane >> 4;
    const int wr  = wv >> 1, wc = wv & 1;

    if (tid < 128) {
        int r = row0 + tid;
        slot_l[tid] = bt[e * T_TOK + ((r < n) ? r : (n - 1))];
    }
    __syncthreads();

    const u16* srcA0 = act + (size_t)slot_l[(wv * 2 + 0) * 16 + l15] * DINT + lhi * 8;
    const u16* srcA1 = act + (size_t)slot_l[(wv * 2 + 1) * 16 + l15] * DINT + lhi * 8;
    const u16* w2 = f2b + (size_t)e * D_IN * DINT;
    const int fb0 = wv * 2, fb1 = wv * 2 + 1;
    const u16* srcB0 = w2 + (size_t)(nt * 128 + fb0 * 16 + l15) * DINT + lhi * 8;
    const u16* srcB1 = w2 + (size_t)(nt * 128 + fb1 * 16 + l15) * DINT + lhi * 8;

    f32x4 acc[4][4];
#pragma unroll
    for (int m = 0; m < 4; m++)
#pragma unroll
        for (int nb = 0; nb < 4; nb++) acc[m][nb] = (f32x4)0.f;

    GLL16(srcA0, &asl[0][fb0 * 512]);
    GLL16(srcA1, &asl[0][fb1 * 512]);
    GLL16(srcB0, &bsl[0][fb0 * 512]);
    GLL16(srcB1, &bsl[0][fb1 * 512]);
    __syncthreads();

#pragma unroll
    for (int ks = 0; ks < 8; ++ks) {
        const int cur = ks & 1;
        if (ks < 7) {
            const int kn = (ks + 1) * 32;
            GLL16(srcA0 + kn, &asl[cur ^ 1][fb0 * 512]);
            GLL16(srcA1 + kn, &asl[cur ^ 1][fb1 * 512]);
            GLL16(srcB0 + kn, &bsl[cur ^ 1][fb0 * 512]);
            GLL16(srcB1 + kn, &bsl[cur ^ 1][fb1 * 512]);
        }
        bf16x8 a[4], b[4];
#pragma unroll
        for (int m = 0; m < 4; m++)
            a[m] = *(const bf16x8*)&asl[cur][(wr * 4 + m) * 512 + lane * 8];
#pragma unroll
        for (int nb = 0; nb < 4; nb++)
            b[nb] = *(const bf16x8*)&bsl[cur][(wc * 4 + nb) * 512 + lane * 8];
#pragma unroll
        for (int m = 0; m < 4; m++)
#pragma unroll
            for (int nb = 0; nb < 4; nb++)
                acc[m][nb] = __builtin_amdgcn_mfma_f32_16x16x32_bf16(
                    a[m], b[nb], acc[m][nb], 0, 0, 0);
        __syncthreads();
    }

#pragma unroll
    for (int m = 0; m < 4; m++) {
#pragma unroll
        for (int j = 0; j < 4; j++) {
            int lrow = wr * 64 + m * 16 + lhi * 4 + j;
            if (row0 + lrow < n) {
                int slot = slot_l[lrow];
                u16* dst = og + (size_t)slot * D_IN + nt * 128 + wc * 64 + l15;
#pragma unroll
                for (int nb = 0; nb < 4; nb++)
                    dst[nb * 16] = f32_bf16(acc[m][nb][j]);
            }
        }
    }
}

// ---------------- 5. combine: z[t] = w0*og[2t] + w1*og[2t+1] ----------------
__global__ __launch_bounds__(256) void combine_kernel(
    const u16* __restrict__ og, const float* __restrict__ wpair,
    float* __restrict__ out)
{
    int idx = blockIdx.x * 256 + threadIdx.x;
    int t  = idx >> 6;
    int c8 = (idx & 63) * 8;
    float w0 = wpair[2 * t], w1 = wpair[2 * t + 1];
    bf16x8 a = *(const bf16x8*)&og[(size_t)(2 * t) * D_IN + c8];
    bf16x8 b = *(const bf16x8*)&og[(size_t)(2 * t + 1) * D_IN + c8];
    float4 o0, o1;
#pragma unroll
    for (int j = 0; j < 4; j++) {
        o0[j] = w0 * bf16_f32((u16)a[j])     + w1 * bf16_f32((u16)b[j]);
        o1[j] = w0 * bf16_f32((u16)a[j + 4]) + w1 * bf16_f32((u16)b[j + 4]);
    }
    float* orow = out + (size_t)t * D_IN + c8;
    *(float4*)orow = o0;
    *(float4*)(orow + 4) = o1;
}

// ---------------- launch ----------------
extern "C" void kernel_launch(void* const* d_in, const int* in_sizes, int n_in,
                              void* d_out, int out_size, void* d_ws, size_t ws_size,
                              hipStream_t stream) {
    const float* x   = (const float*)d_in[0];
    const float* wg  = (const float*)d_in[1];
    const float* fc1 = (const float*)d_in[2];
    const float* fc2 = (const float*)d_in[3];
    float* out = (float*)d_out;
    char* ws = (char*)d_ws;

    int*   cnt   = (int*)(ws + WS_CNT);
    float* wpair = (float*)(ws + WS_WP);
    u16*   bt    = (u16*)(ws + WS_BT);
    u16*   f2b   = (u16*)(ws + WS_F2B);
    u16*   aact  = (u16*)(ws + WS_AA);
    u16*   xb    = (u16*)(ws + WS_XB);
    u16*   f1b   = (u16*)(ws + WS_F1B);
    u16*   og    = (u16*)(ws + WS_OG);

    cvt_kernel<<<1024, 256, 0, stream>>>(fc1, fc2, f1b, f2b, cnt);
    gate_kernel<<<T_TOK / 64, 256, 0, stream>>>(x, wg, cnt, bt, wpair, xb);
    fc1_kernel<<<2048, 256, 0, stream>>>(xb, f1b, cnt, bt, aact);
    fc2_kernel<<<2048, 256, 0, stream>>>(aact, f2b, cnt, bt, og);
    combine_kernel<<<T_TOK * (D_IN / 8) / 256, 256, 0, stream>>>(og, wpair, out);
}

// Round 13
// 83.642 us; speedup vs baseline: 1.1355x; 1.0692x over previous
//
#include <hip/hip_runtime.h>
#include <hip/hip_bf16.h>
#include <stdint.h>

#define T_TOK 8192
#define D_IN  512
#define DINT  256
#define NE    8

typedef float f32x4 __attribute__((ext_vector_type(4)));
typedef short bf16x8 __attribute__((ext_vector_type(8)));
typedef unsigned short u16;
typedef unsigned short u16x4 __attribute__((ext_vector_type(4)));

// ws layout (bytes). og overlays xb+f1s: both dead before fc2 writes og.
#define WS_CNT   0                 // int[8]
#define WS_WP    1024              // f32[16384]         -> 66560
#define WS_BT    66560             // u16[8][8192]       -> 197632
#define WS_F2B   197632            // bf16 fc2 staged (2MB) -> 2294784
#define WS_AA    2294784           // bf16 act [16384][256] (8MB) -> 10683392
#define WS_XB    10683392          // bf16 xb [8192][512] (8MB)   -> 19072000
#define WS_F1B   19072000          // bf16 fc1 staged (4MB) -> 23266304
#define WS_OG    WS_XB             // bf16 og [16384][512] overlay

typedef const __attribute__((address_space(1))) void* gptr_t;
typedef __attribute__((address_space(3))) void* lptr_t;
#define GLL16(g, s) __builtin_amdgcn_global_load_lds((gptr_t)(g), (lptr_t)(s), 16, 0, 0)

static __device__ __forceinline__ u16 f32_bf16(float f) {
    union { float f; uint32_t u; } v; v.f = f;
    uint32_t u = v.u;
    uint32_t r = (u + 0x7FFFu + ((u >> 16) & 1u)) >> 16;   // RTNE
    return (u16)r;
}
static __device__ __forceinline__ float bf16_f32(u16 h) {
    union { uint32_t u; float f; } v; v.u = ((uint32_t)h) << 16; return v.f;
}

// -- 1. cvt: f32 weights -> bf16 in PRE-STAGED fragment layout --------------
// f1s chunk c (8 u16): lane=c&63, f=(c>>6)&7, ks=(c>>9)&15, p=c>>13 (e*4+nt)
//   row = (f<4 ? nt*64+f*16 : 256+nt*64+(f-4)*16) + (lane&15)
//   k   = ks*32 + (lane>>4)*8 .. +7
// f2s chunk c2: lane=c2&63, f=(c2>>6)&7, ks=(c2>>9)&7, p=c2>>12
//   row = nt*128 + f*16 + (lane&15); k = ks*32 + (lane>>4)*8
__global__ __launch_bounds__(256) void cvt_kernel(
    const float* __restrict__ fc1, const float* __restrict__ fc2,
    u16* __restrict__ f1s, u16* __restrict__ f2s, int* __restrict__ cnt)
{
    if (blockIdx.x == 0 && threadIdx.x < NE) cnt[threadIdx.x] = 0;
    const int C1 = NE * 4 * 16 * 512;   // 262144 chunks
    const int C2 = NE * 4 * 8 * 512;    // 131072 chunks
    for (int c = blockIdx.x * 256 + threadIdx.x; c < C1 + C2; c += gridDim.x * 256) {
        const float* s; u16* d;
        if (c < C1) {
            int lane = c & 63, f = (c >> 6) & 7, ks = (c >> 9) & 15, p = c >> 13;
            int e = p >> 2, nt = p & 3;
            int row = ((f < 4) ? (nt * 64 + f * 16) : (256 + nt * 64 + (f - 4) * 16)) + (lane & 15);
            int k = ks * 32 + (lane >> 4) * 8;
            s = fc1 + (size_t)e * 512 * 512 + (size_t)row * 512 + k;
            d = f1s + (size_t)c * 8;
        } else {
            int c2 = c - C1;
            int lane = c2 & 63, f = (c2 >> 6) & 7, ks = (c2 >> 9) & 7, p = c2 >> 12;
            int e = p >> 2, nt = p & 3;
            int row = nt * 128 + f * 16 + (lane & 15);
            int k = ks * 32 + (lane >> 4) * 8;
            s = fc2 + (size_t)e * 512 * 256 + (size_t)row * 256 + k;
            d = f2s + (size_t)c2 * 8;
        }
        float4 v0 = *(const float4*)s;
        float4 v1 = *(const float4*)(s + 4);
        bf16x8 o;
        o[0] = (short)f32_bf16(v0.x); o[1] = (short)f32_bf16(v0.y);
        o[2] = (short)f32_bf16(v0.z); o[3] = (short)f32_bf16(v0.w);
        o[4] = (short)f32_bf16(v1.x); o[5] = (short)f32_bf16(v1.y);
        o[6] = (short)f32_bf16(v1.z); o[7] = (short)f32_bf16(v1.w);
        *(bf16x8*)d = o;
    }
}

// ------- 2. gate: x -> xb (bf16), logits, softmax, top-2, buckets ----------
__global__ __launch_bounds__(256) void gate_kernel(
    const float* __restrict__ x, const float* __restrict__ wg,
    int* __restrict__ cnt, u16* __restrict__ bt, float* __restrict__ wpair,
    u16* __restrict__ xb)
{
    __shared__ float wgl[NE * D_IN];
    __shared__ float xt[64][67];
    __shared__ float part[256 * 9];
    __shared__ int ecnt[NE];
    __shared__ int gbase[NE];

    const int tid = threadIdx.x;
    const int t0  = blockIdx.x * 64;
    const int tl  = tid & 63;
    const int kq  = tid >> 6;

    for (int i = tid; i < NE * D_IN; i += 256) wgl[i] = wg[i];
    if (tid < NE) ecnt[tid] = 0;

    float acc[NE];
#pragma unroll
    for (int e = 0; e < NE; e++) acc[e] = 0.f;

    for (int c = 0; c < 8; ++c) {
        __syncthreads();
#pragma unroll
        for (int i = 0; i < 4; ++i) {
            int idx = i * 256 + tid;
            int row = idx >> 4, c4 = idx & 15;
            float4 v = *(const float4*)&x[(size_t)(t0 + row) * D_IN + c * 64 + c4 * 4];
            u16x4 o;
            o.x = f32_bf16(v.x); o.y = f32_bf16(v.y);
            o.z = f32_bf16(v.z); o.w = f32_bf16(v.w);
            *(u16x4*)&xb[(size_t)(t0 + row) * D_IN + c * 64 + c4 * 4] = o;
            xt[c4 * 4 + 0][row] = v.x; xt[c4 * 4 + 1][row] = v.y;
            xt[c4 * 4 + 2][row] = v.z; xt[c4 * 4 + 3][row] = v.w;
        }
        __syncthreads();
#pragma unroll
        for (int j = 0; j < 16; ++j) {
            float xv = xt[kq * 16 + j][tl];
#pragma unroll
            for (int e = 0; e < NE; e++)
                acc[e] = fmaf(xv, wgl[e * D_IN + c * 64 + kq * 16 + j], acc[e]);
        }
    }
#pragma unroll
    for (int e = 0; e < NE; e++) part[tid * 9 + e] = acc[e];
    __syncthreads();

    int i1 = 0, i2 = -1, lp1 = 0, lp2 = 0;
    if (tid < 64) {
        float s8[NE];
#pragma unroll
        for (int e = 0; e < NE; e++)
            s8[e] = part[tid * 9 + e] + part[(64 + tid) * 9 + e]
                  + part[(128 + tid) * 9 + e] + part[(192 + tid) * 9 + e];
        float m = s8[0];
#pragma unroll
        for (int e = 1; e < NE; e++) m = fmaxf(m, s8[e]);
        float p[NE], s = 0.f;
#pragma unroll
        for (int e = 0; e < NE; e++) { p[e] = expf(s8[e] - m); s += p[e]; }
        float inv = 1.f / s;
        float v1 = p[0];
#pragma unroll
        for (int e = 1; e < NE; e++) if (p[e] > v1) { v1 = p[e]; i1 = e; }
        float v2 = -1.f;
#pragma unroll
        for (int e = 0; e < NE; e++) if (e != i1 && p[e] > v2) { v2 = p[e]; i2 = e; }
        int t = t0 + tid;
        wpair[2 * t]     = v1 * inv;
        wpair[2 * t + 1] = v2 * inv;
        lp1 = atomicAdd(&ecnt[i1], 1);
        lp2 = atomicAdd(&ecnt[i2], 1);
    }
    __syncthreads();
    if (tid < NE) gbase[tid] = atomicAdd(&cnt[tid], ecnt[tid]);
    __syncthreads();
    if (tid < 64) {
        int t = t0 + tid;
        bt[i1 * T_TOK + gbase[i1] + lp1] = (u16)(2 * t);
        bt[i2 * T_TOK + gbase[i2] + lp2] = (u16)(2 * t + 1);
    }
}

// ---------------- 3. fc1 + GLU -> act (slot-indexed) ----------------
// R12 2-phase pipeline; B staged from PRE-STAGED f1s -> each GLL16 is a
// contiguous 1KB load (lane*16B), 16x fewer L2 segments than row-gather.
__global__ __launch_bounds__(256) void fc1_kernel(
    const u16* __restrict__ xb, const u16* __restrict__ f1s,
    const int* __restrict__ cnt, const u16* __restrict__ bt,
    u16* __restrict__ act)
{
    __shared__ __align__(16) u16 asl[2][8 * 512];   // 2 x 8KB
    __shared__ __align__(16) u16 bsl[2][8 * 512];   // 2 x 8KB
    __shared__ u16 slot_l[128];

    const int bid = blockIdx.x;
    const int e   = bid & 7;                     // XCD pinning
    const int nt  = (bid >> 3) & 3;
    const int mt  = bid >> 5;                    // 0..63
    const int n   = cnt[e];
    const int row0 = mt * 128;
    if (row0 >= n) return;

    const int tid = threadIdx.x;
    const int wv  = tid >> 6, lane = tid & 63;
    const int l15 = lane & 15, lhi = lane >> 4;
    const int wr  = wv >> 1, wc = wv & 1;

    if (tid < 128) {
        int r = row0 + tid;
        slot_l[tid] = bt[e * T_TOK + ((r < n) ? r : (n - 1))];
    }
    __syncthreads();

    const u16* srcA0 = xb + (size_t)(slot_l[(wv * 2 + 0) * 16 + l15] >> 1) * D_IN + lhi * 8;
    const u16* srcA1 = xb + (size_t)(slot_l[(wv * 2 + 1) * 16 + l15] >> 1) * D_IN + lhi * 8;
    const int fb0 = wv * 2, fb1 = wv * 2 + 1;
    // pre-staged B: panel (e,nt), stride 4096 u16 per ks, frag fb at fb*512
    const u16* srcB0 = f1s + (size_t)(e * 4 + nt) * 65536 + fb0 * 512 + lane * 8;
    const u16* srcB1 = f1s + (size_t)(e * 4 + nt) * 65536 + fb1 * 512 + lane * 8;

    f32x4 acc[4][4];
#pragma unroll
    for (int m = 0; m < 4; m++)
#pragma unroll
        for (int nb = 0; nb < 4; nb++) acc[m][nb] = (f32x4)0.f;

    // prologue: stage K-step 0 into buffer 0
    GLL16(srcA0, &asl[0][fb0 * 512]);
    GLL16(srcA1, &asl[0][fb1 * 512]);
    GLL16(srcB0, &bsl[0][fb0 * 512]);
    GLL16(srcB1, &bsl[0][fb1 * 512]);
    __syncthreads();

#pragma unroll
    for (int ks = 0; ks < 16; ++ks) {
        const int cur = ks & 1;
        if (ks < 15) {                           // issue next-tile loads first
            GLL16(srcA0 + (ks + 1) * 32,   &asl[cur ^ 1][fb0 * 512]);
            GLL16(srcA1 + (ks + 1) * 32,   &asl[cur ^ 1][fb1 * 512]);
            GLL16(srcB0 + (ks + 1) * 4096, &bsl[cur ^ 1][fb0 * 512]);
            GLL16(srcB1 + (ks + 1) * 4096, &bsl[cur ^ 1][fb1 * 512]);
        }
        bf16x8 a[4], b[4];
#pragma unroll
        for (int m = 0; m < 4; m++)
            a[m] = *(const bf16x8*)&asl[cur][(wr * 4 + m) * 512 + lane * 8];
        b[0] = *(const bf16x8*)&bsl[cur][(wc * 2 + 0) * 512 + lane * 8];
        b[1] = *(const bf16x8*)&bsl[cur][(wc * 2 + 1) * 512 + lane * 8];
        b[2] = *(const bf16x8*)&bsl[cur][(4 + wc * 2 + 0) * 512 + lane * 8];
        b[3] = *(const bf16x8*)&bsl[cur][(4 + wc * 2 + 1) * 512 + lane * 8];
#pragma unroll
        for (int m = 0; m < 4; m++)
#pragma unroll
            for (int nb = 0; nb < 4; nb++)
                acc[m][nb] = __builtin_amdgcn_mfma_f32_16x16x32_bf16(
                    a[m], b[nb], acc[m][nb], 0, 0, 0);
        __syncthreads();   // drains next-tile loads (covered by MFMA) + read fence
    }

    // GLU + store
#pragma unroll
    for (int m = 0; m < 4; m++) {
#pragma unroll
        for (int j = 0; j < 4; j++) {
            int lrow = wr * 64 + m * 16 + lhi * 4 + j;
            if (row0 + lrow < n) {
                int slot = slot_l[lrow];
#pragma unroll
                for (int q = 0; q < 2; q++) {
                    float y = acc[m][q][j], g = acc[m][q + 2][j];
                    float v = y * g / (1.f + __expf(-g));
                    act[(size_t)slot * DINT + nt * 64 + wc * 32 + q * 16 + l15] = f32_bf16(v);
                }
            }
        }
    }
}

// ---------------- 4. fc2 -> og (slot-indexed), 2-phase ----------------
__global__ __launch_bounds__(256) void fc2_kernel(
    const u16* __restrict__ act, const u16* __restrict__ f2s,
    const int* __restrict__ cnt, const u16* __restrict__ bt,
    u16* __restrict__ og)
{
    __shared__ __align__(16) u16 asl[2][8 * 512];
    __shared__ __align__(16) u16 bsl[2][8 * 512];
    __shared__ u16 slot_l[128];

    const int bid = blockIdx.x;
    const int e   = bid & 7;
    const int nt  = (bid >> 3) & 3;
    const int mt  = bid >> 5;
    const int n   = cnt[e];
    const int row0 = mt * 128;
    if (row0 >= n) return;

    const int tid = threadIdx.x;
    const int wv  = tid >> 6, lane = tid & 63;
    const int l15 = lane & 15, lhi = lane >> 4;
    const int wr  = wv >> 1, wc = wv & 1;

    if (tid < 128) {
        int r = row0 + tid;
        slot_l[tid] = bt[e * T_TOK + ((r < n) ? r : (n - 1))];
    }
    __syncthreads();

    const u16* srcA0 = act + (size_t)slot_l[(wv * 2 + 0) * 16 + l15] * DINT + lhi * 8;
    const u16* srcA1 = act + (size_t)slot_l[(wv * 2 + 1) * 16 + l15] * DINT + lhi * 8;
    const int fb0 = wv * 2, fb1 = wv * 2 + 1;
    const u16* srcB0 = f2s + (size_t)(e * 4 + nt) * 32768 + fb0 * 512 + lane * 8;
    const u16* srcB1 = f2s + (size_t)(e * 4 + nt) * 32768 + fb1 * 512 + lane * 8;

    f32x4 acc[4][4];
#pragma unroll
    for (int m = 0; m < 4; m++)
#pragma unroll
        for (int nb = 0; nb < 4; nb++) acc[m][nb] = (f32x4)0.f;

    GLL16(srcA0, &asl[0][fb0 * 512]);
    GLL16(srcA1, &asl[0][fb1 * 512]);
    GLL16(srcB0, &bsl[0][fb0 * 512]);
    GLL16(srcB1, &bsl[0][fb1 * 512]);
    __syncthreads();

#pragma unroll
    for (int ks = 0; ks < 8; ++ks) {
        const int cur = ks & 1;
        if (ks < 7) {
            GLL16(srcA0 + (ks + 1) * 32,   &asl[cur ^ 1][fb0 * 512]);
            GLL16(srcA1 + (ks + 1) * 32,   &asl[cur ^ 1][fb1 * 512]);
            GLL16(srcB0 + (ks + 1) * 4096, &bsl[cur ^ 1][fb0 * 512]);
            GLL16(srcB1 + (ks + 1) * 4096, &bsl[cur ^ 1][fb1 * 512]);
        }
        bf16x8 a[4], b[4];
#pragma unroll
        for (int m = 0; m < 4; m++)
            a[m] = *(const bf16x8*)&asl[cur][(wr * 4 + m) * 512 + lane * 8];
#pragma unroll
        for (int nb = 0; nb < 4; nb++)
            b[nb] = *(const bf16x8*)&bsl[cur][(wc * 4 + nb) * 512 + lane * 8];
#pragma unroll
        for (int m = 0; m < 4; m++)
#pragma unroll
            for (int nb = 0; nb < 4; nb++)
                acc[m][nb] = __builtin_amdgcn_mfma_f32_16x16x32_bf16(
                    a[m], b[nb], acc[m][nb], 0, 0, 0);
        __syncthreads();
    }

#pragma unroll
    for (int m = 0; m < 4; m++) {
#pragma unroll
        for (int j = 0; j < 4; j++) {
            int lrow = wr * 64 + m * 16 + lhi * 4 + j;
            if (row0 + lrow < n) {
                int slot = slot_l[lrow];
                u16* dst = og + (size_t)slot * D_IN + nt * 128 + wc * 64 + l15;
#pragma unroll
                for (int nb = 0; nb < 4; nb++)
                    dst[nb * 16] = f32_bf16(acc[m][nb][j]);
            }
        }
    }
}

// ---------------- 5. combine: z[t] = w0*og[2t] + w1*og[2t+1] ----------------
__global__ __launch_bounds__(256) void combine_kernel(
    const u16* __restrict__ og, const float* __restrict__ wpair,
    float* __restrict__ out)
{
    int idx = blockIdx.x * 256 + threadIdx.x;
    int t  = idx >> 6;
    int c8 = (idx & 63) * 8;
    float w0 = wpair[2 * t], w1 = wpair[2 * t + 1];
    bf16x8 a = *(const bf16x8*)&og[(size_t)(2 * t) * D_IN + c8];
    bf16x8 b = *(const bf16x8*)&og[(size_t)(2 * t + 1) * D_IN + c8];
    float4 o0, o1;
#pragma unroll
    for (int j = 0; j < 4; j++) {
        o0[j] = w0 * bf16_f32((u16)a[j])     + w1 * bf16_f32((u16)b[j]);
        o1[j] = w0 * bf16_f32((u16)a[j + 4]) + w1 * bf16_f32((u16)b[j + 4]);
    }
    float* orow = out + (size_t)t * D_IN + c8;
    *(float4*)orow = o0;
    *(float4*)(orow + 4) = o1;
}

// ---------------- launch ----------------
extern "C" void kernel_launch(void* const* d_in, const int* in_sizes, int n_in,
                              void* d_out, int out_size, void* d_ws, size_t ws_size,
                              hipStream_t stream) {
    const float* x   = (const float*)d_in[0];
    const float* wg  = (const float*)d_in[1];
    const float* fc1 = (const float*)d_in[2];
    const float* fc2 = (const float*)d_in[3];
    float* out = (float*)d_out;
    char* ws = (char*)d_ws;

    int*   cnt   = (int*)(ws + WS_CNT);
    float* wpair = (float*)(ws + WS_WP);
    u16*   bt    = (u16*)(ws + WS_BT);
    u16*   f2s   = (u16*)(ws + WS_F2B);
    u16*   aact  = (u16*)(ws + WS_AA);
    u16*   xb    = (u16*)(ws + WS_XB);
    u16*   f1s   = (u16*)(ws + WS_F1B);
    u16*   og    = (u16*)(ws + WS_OG);

    cvt_kernel<<<1024, 256, 0, stream>>>(fc1, fc2, f1s, f2s, cnt);
    gate_kernel<<<T_TOK / 64, 256, 0, stream>>>(x, wg, cnt, bt, wpair, xb);
    fc1_kernel<<<2048, 256, 0, stream>>>(xb, f1s, cnt, bt, aact);
    fc2_kernel<<<2048, 256, 0, stream>>>(aact, f2s, cnt, bt, og);
    combine_kernel<<<T_TOK * (D_IN / 8) / 256, 256, 0, stream>>>(og, wpair, out);
}

// Round 14
// 76.012 us; speedup vs baseline: 1.2495x; 1.1004x over previous
//
#include <hip/hip_runtime.h>
#include <hip/hip_bf16.h>
#include <stdint.h>

#define T_TOK 8192
#define D_IN  512
#define DINT  256
#define NE    8

typedef float f32x4 __attribute__((ext_vector_type(4)));
typedef short bf16x8 __attribute__((ext_vector_type(8)));
typedef unsigned short u16;
typedef unsigned short u16x4 __attribute__((ext_vector_type(4)));

// ws layout (bytes) — ws is ~256MB (poison fill WRITE_SIZE), no overlays needed
#define WS_CNT   0                 // int[8]
#define WS_WP    1024              // f32[16384]           -> 66560
#define WS_BT    66560             // u16[8][8192]         -> 197632
#define WS_F2B   197632            // bf16 fc2 staged (2MB)-> 2294784
#define WS_F1B   2294784           // bf16 fc1 staged (4MB)-> 6489088
#define WS_XB    6489088           // bf16 xb [8192][512]  -> 14877696
#define WS_AS    14877696          // bf16 act staged, 135 tiles x 64KB -> 23725056
#define WS_OG    23725056          // bf16 og [16384][512] -> 40502272

typedef const __attribute__((address_space(1))) void* gptr_t;
typedef __attribute__((address_space(3))) void* lptr_t;
#define GLL16(g, s) __builtin_amdgcn_global_load_lds((gptr_t)(g), (lptr_t)(s), 16, 0, 0)

static __device__ __forceinline__ u16 f32_bf16(float f) {
    union { float f; uint32_t u; } v; v.f = f;
    uint32_t u = v.u;
    uint32_t r = (u + 0x7FFFu + ((u >> 16) & 1u)) >> 16;   // RTNE
    return (u16)r;
}
static __device__ __forceinline__ float bf16_f32(u16 h) {
    union { uint32_t u; float f; } v; v.u = ((uint32_t)h) << 16; return v.f;
}

// -- 1. cvt: f32 weights -> bf16 in PRE-STAGED fragment layout (as R13) -----
__global__ __launch_bounds__(256) void cvt_kernel(
    const float* __restrict__ fc1, const float* __restrict__ fc2,
    u16* __restrict__ f1s, u16* __restrict__ f2s, int* __restrict__ cnt)
{
    if (blockIdx.x == 0 && threadIdx.x < NE) cnt[threadIdx.x] = 0;
    const int C1 = NE * 4 * 16 * 512;
    const int C2 = NE * 4 * 8 * 512;
    for (int c = blockIdx.x * 256 + threadIdx.x; c < C1 + C2; c += gridDim.x * 256) {
        const float* s; u16* d;
        if (c < C1) {
            int lane = c & 63, f = (c >> 6) & 7, ks = (c >> 9) & 15, p = c >> 13;
            int e = p >> 2, nt = p & 3;
            int row = ((f < 4) ? (nt * 64 + f * 16) : (256 + nt * 64 + (f - 4) * 16)) + (lane & 15);
            int k = ks * 32 + (lane >> 4) * 8;
            s = fc1 + (size_t)e * 512 * 512 + (size_t)row * 512 + k;
            d = f1s + (size_t)c * 8;
        } else {
            int c2 = c - C1;
            int lane = c2 & 63, f = (c2 >> 6) & 7, ks = (c2 >> 9) & 7, p = c2 >> 12;
            int e = p >> 2, nt = p & 3;
            int row = nt * 128 + f * 16 + (lane & 15);
            int k = ks * 32 + (lane >> 4) * 8;
            s = fc2 + (size_t)e * 512 * 256 + (size_t)row * 256 + k;
            d = f2s + (size_t)c2 * 8;
        }
        float4 v0 = *(const float4*)s;
        float4 v1 = *(const float4*)(s + 4);
        bf16x8 o;
        o[0] = (short)f32_bf16(v0.x); o[1] = (short)f32_bf16(v0.y);
        o[2] = (short)f32_bf16(v0.z); o[3] = (short)f32_bf16(v0.w);
        o[4] = (short)f32_bf16(v1.x); o[5] = (short)f32_bf16(v1.y);
        o[6] = (short)f32_bf16(v1.z); o[7] = (short)f32_bf16(v1.w);
        *(bf16x8*)d = o;
    }
}

// ------- 2. gate (identical to R13) ----------------------------------------
__global__ __launch_bounds__(256) void gate_kernel(
    const float* __restrict__ x, const float* __restrict__ wg,
    int* __restrict__ cnt, u16* __restrict__ bt, float* __restrict__ wpair,
    u16* __restrict__ xb)
{
    __shared__ float wgl[NE * D_IN];
    __shared__ float xt[64][67];
    __shared__ float part[256 * 9];
    __shared__ int ecnt[NE];
    __shared__ int gbase[NE];

    const int tid = threadIdx.x;
    const int t0  = blockIdx.x * 64;
    const int tl  = tid & 63;
    const int kq  = tid >> 6;

    for (int i = tid; i < NE * D_IN; i += 256) wgl[i] = wg[i];
    if (tid < NE) ecnt[tid] = 0;

    float acc[NE];
#pragma unroll
    for (int e = 0; e < NE; e++) acc[e] = 0.f;

    for (int c = 0; c < 8; ++c) {
        __syncthreads();
#pragma unroll
        for (int i = 0; i < 4; ++i) {
            int idx = i * 256 + tid;
            int row = idx >> 4, c4 = idx & 15;
            float4 v = *(const float4*)&x[(size_t)(t0 + row) * D_IN + c * 64 + c4 * 4];
            u16x4 o;
            o.x = f32_bf16(v.x); o.y = f32_bf16(v.y);
            o.z = f32_bf16(v.z); o.w = f32_bf16(v.w);
            *(u16x4*)&xb[(size_t)(t0 + row) * D_IN + c * 64 + c4 * 4] = o;
            xt[c4 * 4 + 0][row] = v.x; xt[c4 * 4 + 1][row] = v.y;
            xt[c4 * 4 + 2][row] = v.z; xt[c4 * 4 + 3][row] = v.w;
        }
        __syncthreads();
#pragma unroll
        for (int j = 0; j < 16; ++j) {
            float xv = xt[kq * 16 + j][tl];
#pragma unroll
            for (int e = 0; e < NE; e++)
                acc[e] = fmaf(xv, wgl[e * D_IN + c * 64 + kq * 16 + j], acc[e]);
        }
    }
#pragma unroll
    for (int e = 0; e < NE; e++) part[tid * 9 + e] = acc[e];
    __syncthreads();

    int i1 = 0, i2 = -1, lp1 = 0, lp2 = 0;
    if (tid < 64) {
        float s8[NE];
#pragma unroll
        for (int e = 0; e < NE; e++)
            s8[e] = part[tid * 9 + e] + part[(64 + tid) * 9 + e]
                  + part[(128 + tid) * 9 + e] + part[(192 + tid) * 9 + e];
        float m = s8[0];
#pragma unroll
        for (int e = 1; e < NE; e++) m = fmaxf(m, s8[e]);
        float p[NE], s = 0.f;
#pragma unroll
        for (int e = 0; e < NE; e++) { p[e] = expf(s8[e] - m); s += p[e]; }
        float inv = 1.f / s;
        float v1 = p[0];
#pragma unroll
        for (int e = 1; e < NE; e++) if (p[e] > v1) { v1 = p[e]; i1 = e; }
        float v2 = -1.f;
#pragma unroll
        for (int e = 0; e < NE; e++) if (e != i1 && p[e] > v2) { v2 = p[e]; i2 = e; }
        int t = t0 + tid;
        wpair[2 * t]     = v1 * inv;
        wpair[2 * t + 1] = v2 * inv;
        lp1 = atomicAdd(&ecnt[i1], 1);
        lp2 = atomicAdd(&ecnt[i2], 1);
    }
    __syncthreads();
    if (tid < NE) gbase[tid] = atomicAdd(&cnt[tid], ecnt[tid]);
    __syncthreads();
    if (tid < 64) {
        int t = t0 + tid;
        bt[i1 * T_TOK + gbase[i1] + lp1] = (u16)(2 * t);
        bt[i2 * T_TOK + gbase[i2] + lp2] = (u16)(2 * t + 1);
    }
}

// ---------------- 3. fc1 + GLU -> act_s (fragment-staged) ----------------
// R13 2-phase loop; epilogue routes GLU tile through LDS and stores it in
// fc2's A-fragment layout: tile g=(tpre+mt): [ks 0..7][mf 0..7][lane][8].
__global__ __launch_bounds__(256) void fc1_kernel(
    const u16* __restrict__ xb, const u16* __restrict__ f1s,
    const int* __restrict__ cnt, const u16* __restrict__ bt,
    u16* __restrict__ acts)
{
    __shared__ __align__(16) u16 shm[16384];     // asl 2x4096 | bsl 2x4096 (32KB)
    __shared__ u16 slot_l[128];

    const int bid = blockIdx.x;
    const int e   = bid & 7;
    const int nt  = (bid >> 3) & 3;
    const int mt  = bid >> 5;
    const int n   = cnt[e];
    const int row0 = mt * 128;
    if (row0 >= n) return;

    int tpre = 0;
#pragma unroll
    for (int ee = 0; ee < NE; ++ee)
        if (ee < e) tpre += (cnt[ee] + 127) >> 7;

    const int tid = threadIdx.x;
    const int wv  = tid >> 6, lane = tid & 63;
    const int l15 = lane & 15, lhi = lane >> 4;
    const int wr  = wv >> 1, wc = wv & 1;

    if (tid < 128) {
        int r = row0 + tid;
        slot_l[tid] = bt[e * T_TOK + ((r < n) ? r : (n - 1))];
    }
    __syncthreads();

    u16* asl = shm;                // [2][4096]
    u16* bsl = shm + 8192;         // [2][4096]

    const u16* srcA0 = xb + (size_t)(slot_l[(wv * 2 + 0) * 16 + l15] >> 1) * D_IN + lhi * 8;
    const u16* srcA1 = xb + (size_t)(slot_l[(wv * 2 + 1) * 16 + l15] >> 1) * D_IN + lhi * 8;
    const int fb0 = wv * 2, fb1 = wv * 2 + 1;
    const u16* srcB0 = f1s + (size_t)(e * 4 + nt) * 65536 + fb0 * 512 + lane * 8;
    const u16* srcB1 = f1s + (size_t)(e * 4 + nt) * 65536 + fb1 * 512 + lane * 8;

    f32x4 acc[4][4];
#pragma unroll
    for (int m = 0; m < 4; m++)
#pragma unroll
        for (int nb = 0; nb < 4; nb++) acc[m][nb] = (f32x4)0.f;

    GLL16(srcA0, &asl[0 * 4096 + fb0 * 512]);
    GLL16(srcA1, &asl[0 * 4096 + fb1 * 512]);
    GLL16(srcB0, &bsl[0 * 4096 + fb0 * 512]);
    GLL16(srcB1, &bsl[0 * 4096 + fb1 * 512]);
    __syncthreads();

#pragma unroll
    for (int ks = 0; ks < 16; ++ks) {
        const int cur = ks & 1;
        if (ks < 15) {
            GLL16(srcA0 + (ks + 1) * 32,   &asl[(cur ^ 1) * 4096 + fb0 * 512]);
            GLL16(srcA1 + (ks + 1) * 32,   &asl[(cur ^ 1) * 4096 + fb1 * 512]);
            GLL16(srcB0 + (ks + 1) * 4096, &bsl[(cur ^ 1) * 4096 + fb0 * 512]);
            GLL16(srcB1 + (ks + 1) * 4096, &bsl[(cur ^ 1) * 4096 + fb1 * 512]);
        }
        bf16x8 a[4], b[4];
#pragma unroll
        for (int m = 0; m < 4; m++)
            a[m] = *(const bf16x8*)&asl[cur * 4096 + (wr * 4 + m) * 512 + lane * 8];
        b[0] = *(const bf16x8*)&bsl[cur * 4096 + (wc * 2 + 0) * 512 + lane * 8];
        b[1] = *(const bf16x8*)&bsl[cur * 4096 + (wc * 2 + 1) * 512 + lane * 8];
        b[2] = *(const bf16x8*)&bsl[cur * 4096 + (4 + wc * 2 + 0) * 512 + lane * 8];
        b[3] = *(const bf16x8*)&bsl[cur * 4096 + (4 + wc * 2 + 1) * 512 + lane * 8];
#pragma unroll
        for (int m = 0; m < 4; m++)
#pragma unroll
            for (int nb = 0; nb < 4; nb++)
                acc[m][nb] = __builtin_amdgcn_mfma_f32_16x16x32_bf16(
                    a[m], b[nb], acc[m][nb], 0, 0, 0);
        __syncthreads();
    }

    // GLU -> LDS [128][72] (stride-72 u16: <=2-way banks), then coalesced store
#pragma unroll
    for (int m = 0; m < 4; m++) {
#pragma unroll
        for (int j = 0; j < 4; j++) {
            int row = wr * 64 + m * 16 + lhi * 4 + j;
#pragma unroll
            for (int q = 0; q < 2; q++) {
                float y = acc[m][q][j], g = acc[m][q + 2][j];
                float v = y * g / (1.f + __expf(-g));
                shm[row * 72 + wc * 32 + q * 16 + l15] = f32_bf16(v);
            }
        }
    }
    __syncthreads();

    u16* tile = acts + (size_t)(tpre + mt) * 32768;
#pragma unroll
    for (int i = 0; i < 4; ++i) {
        int c = wv * 4 + i;
        int mf = c >> 1, ksr = c & 1;
        bf16x8 v = *(const bf16x8*)&shm[(mf * 16 + l15) * 72 + ksr * 32 + lhi * 8];
        *(bf16x8*)&tile[(2 * nt + ksr) * 4096 + mf * 512 + lane * 8] = v;
    }
}

// ------------- 4. fc2 -> og: A AND B both contiguous pre-staged -------------
__global__ __launch_bounds__(256) void fc2_kernel(
    const u16* __restrict__ acts, const u16* __restrict__ f2s,
    const int* __restrict__ cnt, const u16* __restrict__ bt,
    u16* __restrict__ og)
{
    __shared__ __align__(16) u16 asl[2][8 * 512];
    __shared__ __align__(16) u16 bsl[2][8 * 512];
    __shared__ u16 slot_l[128];

    const int bid = blockIdx.x;
    const int e   = bid & 7;
    const int nt  = (bid >> 3) & 3;
    const int mt  = bid >> 5;
    const int n   = cnt[e];
    const int row0 = mt * 128;
    if (row0 >= n) return;

    int tpre = 0;
#pragma unroll
    for (int ee = 0; ee < NE; ++ee)
        if (ee < e) tpre += (cnt[ee] + 127) >> 7;

    const int tid = threadIdx.x;
    const int wv  = tid >> 6, lane = tid & 63;
    const int l15 = lane & 15, lhi = lane >> 4;
    const int wr  = wv >> 1, wc = wv & 1;

    if (tid < 128) {
        int r = row0 + tid;
        slot_l[tid] = bt[e * T_TOK + ((r < n) ? r : (n - 1))];
    }
    __syncthreads();

    const int fb0 = wv * 2, fb1 = wv * 2 + 1;
    const u16* srcA0 = acts + (size_t)(tpre + mt) * 32768 + fb0 * 512 + lane * 8;
    const u16* srcA1 = acts + (size_t)(tpre + mt) * 32768 + fb1 * 512 + lane * 8;
    const u16* srcB0 = f2s + (size_t)(e * 4 + nt) * 32768 + fb0 * 512 + lane * 8;
    const u16* srcB1 = f2s + (size_t)(e * 4 + nt) * 32768 + fb1 * 512 + lane * 8;

    f32x4 acc[4][4];
#pragma unroll
    for (int m = 0; m < 4; m++)
#pragma unroll
        for (int nb = 0; nb < 4; nb++) acc[m][nb] = (f32x4)0.f;

    GLL16(srcA0, &asl[0][fb0 * 512]);
    GLL16(srcA1, &asl[0][fb1 * 512]);
    GLL16(srcB0, &bsl[0][fb0 * 512]);
    GLL16(srcB1, &bsl[0][fb1 * 512]);
    __syncthreads();

#pragma unroll
    for (int ks = 0; ks < 8; ++ks) {
        const int cur = ks & 1;
        if (ks < 7) {
            GLL16(srcA0 + (ks + 1) * 4096, &asl[cur ^ 1][fb0 * 512]);
            GLL16(srcA1 + (ks + 1) * 4096, &asl[cur ^ 1][fb1 * 512]);
            GLL16(srcB0 + (ks + 1) * 4096, &bsl[cur ^ 1][fb0 * 512]);
            GLL16(srcB1 + (ks + 1) * 4096, &bsl[cur ^ 1][fb1 * 512]);
        }
        bf16x8 a[4], b[4];
#pragma unroll
        for (int m = 0; m < 4; m++)
            a[m] = *(const bf16x8*)&asl[cur][(wr * 4 + m) * 512 + lane * 8];
#pragma unroll
        for (int nb = 0; nb < 4; nb++)
            b[nb] = *(const bf16x8*)&bsl[cur][(wc * 4 + nb) * 512 + lane * 8];
#pragma unroll
        for (int m = 0; m < 4; m++)
#pragma unroll
            for (int nb = 0; nb < 4; nb++)
                acc[m][nb] = __builtin_amdgcn_mfma_f32_16x16x32_bf16(
                    a[m], b[nb], acc[m][nb], 0, 0, 0);
        __syncthreads();
    }

#pragma unroll
    for (int m = 0; m < 4; m++) {
#pragma unroll
        for (int j = 0; j < 4; j++) {
            int lrow = wr * 64 + m * 16 + lhi * 4 + j;
            if (row0 + lrow < n) {
                int slot = slot_l[lrow];
                u16* dst = og + (size_t)slot * D_IN + nt * 128 + wc * 64 + l15;
#pragma unroll
                for (int nb = 0; nb < 4; nb++)
                    dst[nb * 16] = f32_bf16(acc[m][nb][j]);
            }
        }
    }
}

// ---------------- 5. combine (identical to R13) ----------------
__global__ __launch_bounds__(256) void combine_kernel(
    const u16* __restrict__ og, const float* __restrict__ wpair,
    float* __restrict__ out)
{
    int idx = blockIdx.x * 256 + threadIdx.x;
    int t  = idx >> 6;
    int c8 = (idx & 63) * 8;
    float w0 = wpair[2 * t], w1 = wpair[2 * t + 1];
    bf16x8 a = *(const bf16x8*)&og[(size_t)(2 * t) * D_IN + c8];
    bf16x8 b = *(const bf16x8*)&og[(size_t)(2 * t + 1) * D_IN + c8];
    float4 o0, o1;
#pragma unroll
    for (int j = 0; j < 4; j++) {
        o0[j] = w0 * bf16_f32((u16)a[j])     + w1 * bf16_f32((u16)b[j]);
        o1[j] = w0 * bf16_f32((u16)a[j + 4]) + w1 * bf16_f32((u16)b[j + 4]);
    }
    float* orow = out + (size_t)t * D_IN + c8;
    *(float4*)orow = o0;
    *(float4*)(orow + 4) = o1;
}

// ---------------- launch ----------------
extern "C" void kernel_launch(void* const* d_in, const int* in_sizes, int n_in,
                              void* d_out, int out_size, void* d_ws, size_t ws_size,
                              hipStream_t stream) {
    const float* x   = (const float*)d_in[0];
    const float* wg  = (const float*)d_in[1];
    const float* fc1 = (const float*)d_in[2];
    const float* fc2 = (const float*)d_in[3];
    float* out = (float*)d_out;
    char* ws = (char*)d_ws;

    int*   cnt   = (int*)(ws + WS_CNT);
    float* wpair = (float*)(ws + WS_WP);
    u16*   bt    = (u16*)(ws + WS_BT);
    u16*   f2s   = (u16*)(ws + WS_F2B);
    u16*   f1s   = (u16*)(ws + WS_F1B);
    u16*   xb    = (u16*)(ws + WS_XB);
    u16*   acts  = (u16*)(ws + WS_AS);
    u16*   og    = (u16*)(ws + WS_OG);

    cvt_kernel<<<1024, 256, 0, stream>>>(fc1, fc2, f1s, f2s, cnt);
    gate_kernel<<<T_TOK / 64, 256, 0, stream>>>(x, wg, cnt, bt, wpair, xb);
    fc1_kernel<<<2048, 256, 0, stream>>>(xb, f1s, cnt, bt, acts);
    fc2_kernel<<<2048, 256, 0, stream>>>(acts, f2s, cnt, bt, og);
    combine_kernel<<<T_TOK * (D_IN / 8) / 256, 256, 0, stream>>>(og, wpair, out);
}